// Round 10
// baseline (129.859 us; speedup 1.0000x reference)
//
#include <hip/hip_runtime.h>
#include <hip/hip_bf16.h>

// Problem constants (fixed by setup_inputs): B=8, T=2048, D=1024, positions in [0,64).
#define NB 8
#define NT 2048
#define ND 1024
#define CAP 2048       // max tokens per bucket (worst case all T in one bucket)

typedef unsigned short ushort_t;

__device__ __forceinline__ ushort_t f2bf(float f) {
    __hip_bfloat16 h = __float2bfloat16(f);
    return *reinterpret_cast<ushort_t*>(&h);
}
__device__ __forceinline__ float bf2f(ushort_t u) {
    unsigned int v = ((unsigned int)u) << 16;
    return __int_as_float((int)v);
}

// ---------------------------------------------------------------------------
// Workspace layout (byte offsets):
//   pad    : 64 floats of zeros (also used as the masked-lane g window)   @ 0
//   G2f    : 128 floats  g2[k] = exp(-(k-63)^2/512), valid k in [0,126]   @ 256
//   cntv   : NB*64 int                                                    @ 768
//   cnth   : NB*64 int                                                    @ 2816
//   invden : NB*64*64 float                                               @ 4864
//   tokv   : NB*64*CAP int   packed (t | posh[t]<<16), bucketed by posv   @ 135936
//   tokh   : NB*64*CAP int   packed (t | posv[t]<<16), bucketed by posh   @ 4330240
//   B1     : NB*64*64*1024 bf16   [b][q=ph'][pv][d]                       @ 8524544
// ---------------------------------------------------------------------------
#define OFF_G2     256
#define OFF_CNTV   768
#define OFF_CNTH   2816
#define OFF_INVDEN 4864
#define OFF_TOKV   135936
#define OFF_TOKH   4330240
#define OFF_B1     8524544
#define B1_SLAB    ((size_t)64 * 64 * 1024 * 2)   // bytes per batch slab (8 MB, bf16)

// K1: deterministic CSR bucket lists via wave ballot compaction (no atomics).
// Entries packed: t | (other_axis_pos[t] << 16). Block 0 fills the g table.
__global__ __launch_bounds__(256) void k1_bucket(
    const int* __restrict__ posv, const int* __restrict__ posh,
    int* __restrict__ tokv, int* __restrict__ tokh,
    int* __restrict__ cntv, int* __restrict__ cnth,
    float* __restrict__ gbase)   // = ws base; table lives at gbase+64
{
    int b    = blockIdx.x >> 5;      // NB*32 blocks
    int blk  = blockIdx.x & 31;
    int wave = threadIdx.x >> 6;
    int lane = threadIdx.x & 63;

    if (blockIdx.x == 0 && threadIdx.x < 192) {
        int k = (int)threadIdx.x - 64;     // table index; <0 = pad
        float v = 0.0f;
        if (k >= 0 && k < 127) {
            int r = k - 63;
            v = expf(-(float)(r * r) * (1.0f / 512.0f));
        }
        gbase[threadIdx.x] = v;
    }

    int task   = blk * 4 + wave;                // 0..127
    int bucket = task & 63;
    int use_ph = task >> 6;
    const int* pos  = use_ph ? posh : posv;
    const int* opos = use_ph ? posv : posh;
    int* tok = (use_ph ? tokh : tokv) + ((size_t)(b * 64 + bucket)) * CAP;
    int* cnt = use_ph ? cnth : cntv;

    int vals[32];
#pragma unroll
    for (int k = 0; k < 32; k++) vals[k] = pos[b * NT + k * 64 + lane];

    unsigned long long lmask = (1ull << lane) - 1ull;
    int cursor = 0;
#pragma unroll 4
    for (int k = 0; k < 32; k++) {
        bool hit = (vals[k] == bucket);
        unsigned long long m = __ballot(hit);
        if (hit) {
            int t = k * 64 + lane;
            tok[cursor + __popcll(m & lmask)] = t | (opos[b * NT + t] << 16);
        }
        cursor += (int)__popcll(m);
    }
    if (lane == 0) cnt[b * 64 + bucket] = cursor;
}

// KDEN: denominator table. den[pv][ph] = sum_{j,k} hist[j][k] g(pv-j) g(ph-k).
__global__ __launch_bounds__(256) void kden(
    const int* __restrict__ posv, const int* __restrict__ posh,
    const float* __restrict__ G2f, float* __restrict__ invden, int b0)
{
    int b   = b0 + (blockIdx.x >> 3);
    int phg = blockIdx.x & 7;
    int tid = threadIdx.x;

    __shared__ int   hist[64][64];
    __shared__ float g2s[128];
    __shared__ float tmp[64][8];

#pragma unroll
    for (int k = 0; k < 16; k++) ((int*)hist)[tid + (k << 8)] = 0;
    if (tid < 128) g2s[tid] = G2f[tid];
    __syncthreads();
#pragma unroll
    for (int k = 0; k < 8; k++) {
        int t = (k << 8) + tid;
        atomicAdd(&hist[posv[b * NT + t]][posh[b * NT + t]], 1);
    }
    __syncthreads();
#pragma unroll
    for (int c = 0; c < 2; c++) {
        int cell = (c << 8) + tid;        // 512 cells: 64 j x 8 phl
        int j    = cell >> 3;
        int phl  = cell & 7;
        int ph   = (phg << 3) + phl;
        float s = 0.f;
        for (int k = 0; k < 64; k++)
            s += (float)hist[j][k] * g2s[63 + k - ph];
        tmp[j][phl] = s;
    }
    __syncthreads();
#pragma unroll
    for (int c = 0; c < 2; c++) {
        int cell = (c << 8) + tid;
        int pv   = cell >> 3;
        int phl  = cell & 7;
        int ph   = (phg << 3) + phl;
        float s = 0.f;
        for (int j = 0; j < 64; j++)
            s += g2s[63 + j - pv] * tmp[j][phl];
        invden[(b * 64 + pv) * 64 + ph] = 1.0f / s;
    }
}

// K2: h-conv from packed token lists — LATENCY-PIPELINED (round-9 fix).
// Rounds 8/9 stalled 72%: per token the compiler emitted a serial
// load(toks)->readfirstlane->load(x)->FMA round trip (~600cy). Here token
// meta comes in as two int4 loads per 8-token chunk and the loop runs a
// depth-2 software pipeline: meta[c+2] and x[c+1] issue before chunk c's
// 128 FMAs. Per-thread state ~50 VGPR (acc16+xv8+xn8) — small enough that
// regalloc has no motive to re-serialize (round-8 precedent: acc[16] held).
// Partial chunks: uniform mask, g window -> zero pad (no divergence).
__global__ __launch_bounds__(256) void k2_convh(
    const float* __restrict__ x,
    const int* __restrict__ tokv, const int* __restrict__ cntv,
    const float* __restrict__ G2f, ushort_t* __restrict__ B1, int b0)
{
    int pv   = blockIdx.x & 63;
    int dc   = (blockIdx.x >> 6) & 15;
    int b    = b0 + (blockIdx.x >> 10);
    int tid  = threadIdx.x;
    int lane = tid & 63;
    int goff = __builtin_amdgcn_readfirstlane(63 + ((tid >> 6) << 4));  // 63+16w
    int wq   = goff - 63;                                               // 16w
    int d0   = (dc << 6) + lane;

    const float* xb = x + (((size_t)b * NT) << 10) + d0;
    int n = cntv[b * 64 + pv];
    const int* toks = tokv + ((size_t)(b * 64 + pv)) * CAP;
    const float* gzero = G2f - 64;   // 16 zeros in the pad region

    float acc[16];
#pragma unroll
    for (int q = 0; q < 16; q++) acc[q] = 0.f;

    if (n > 0) {
        int nch = (n + 7) >> 3;
        int pk0[8], pk1[8];
        float xv[8];

        // prologue: meta chunk 0 (reads past n are memory-safe: ws is mapped)
        {
            int4 A  = *(const int4*)(toks);
            int4 Bv = *(const int4*)(toks + 4);
            pk0[0] = __builtin_amdgcn_readfirstlane(A.x);
            pk0[1] = __builtin_amdgcn_readfirstlane(A.y);
            pk0[2] = __builtin_amdgcn_readfirstlane(A.z);
            pk0[3] = __builtin_amdgcn_readfirstlane(A.w);
            pk0[4] = __builtin_amdgcn_readfirstlane(Bv.x);
            pk0[5] = __builtin_amdgcn_readfirstlane(Bv.y);
            pk0[6] = __builtin_amdgcn_readfirstlane(Bv.z);
            pk0[7] = __builtin_amdgcn_readfirstlane(Bv.w);
        }
        // x chunk 0 — 8 independent gathers
#pragma unroll
        for (int j = 0; j < 8; j++) {
            int t = (j < n) ? (pk0[j] & 0xffff) : 0;
            xv[j] = xb[(size_t)t << 10];
        }
        // meta chunk 1
        {
            int4 A  = *(const int4*)(toks + 8);
            int4 Bv = *(const int4*)(toks + 12);
            pk1[0] = __builtin_amdgcn_readfirstlane(A.x);
            pk1[1] = __builtin_amdgcn_readfirstlane(A.y);
            pk1[2] = __builtin_amdgcn_readfirstlane(A.z);
            pk1[3] = __builtin_amdgcn_readfirstlane(A.w);
            pk1[4] = __builtin_amdgcn_readfirstlane(Bv.x);
            pk1[5] = __builtin_amdgcn_readfirstlane(Bv.y);
            pk1[6] = __builtin_amdgcn_readfirstlane(Bv.z);
            pk1[7] = __builtin_amdgcn_readfirstlane(Bv.w);
        }

        for (int c = 0; c < nch; ++c) {
            int i = c << 3;
            // prefetch meta chunk c+2
            int4 A2 = *(const int4*)(toks + i + 16);
            int4 B2 = *(const int4*)(toks + i + 20);
            // prefetch x chunk c+1 (masked by uniform bounds)
            float xn[8];
#pragma unroll
            for (int j = 0; j < 8; j++) {
                int t = (i + 8 + j < n) ? (pk1[j] & 0xffff) : 0;
                xn[j] = xb[(size_t)t << 10];
            }
            // FMAs for chunk c; masked lanes hit the zero-pad g window
            const float* gp[8];
#pragma unroll
            for (int j = 0; j < 8; j++)
                gp[j] = (i + j < n) ? (G2f + (goff - (pk0[j] >> 16))) : gzero;
#pragma unroll
            for (int q = 0; q < 16; q++) {
                float a = acc[q];
#pragma unroll
                for (int j = 0; j < 8; j++)
                    a = fmaf(gp[j][q], xv[j], a);
                acc[q] = a;
            }
            // rotate pipeline state
#pragma unroll
            for (int j = 0; j < 8; j++) { pk0[j] = pk1[j]; xv[j] = xn[j]; }
            pk1[0] = __builtin_amdgcn_readfirstlane(A2.x);
            pk1[1] = __builtin_amdgcn_readfirstlane(A2.y);
            pk1[2] = __builtin_amdgcn_readfirstlane(A2.z);
            pk1[3] = __builtin_amdgcn_readfirstlane(A2.w);
            pk1[4] = __builtin_amdgcn_readfirstlane(B2.x);
            pk1[5] = __builtin_amdgcn_readfirstlane(B2.y);
            pk1[6] = __builtin_amdgcn_readfirstlane(B2.z);
            pk1[7] = __builtin_amdgcn_readfirstlane(B2.w);
        }
    }

    // B1[b][q][pv][d] (bf16), q = wq + qi
    ushort_t* B1p = B1 + (((size_t)(b - b0)) << 22) + (((size_t)wq) << 16)
                  + (((size_t)pv) << 10) + d0;
#pragma unroll
    for (int q = 0; q < 16; q++)
        B1p[(size_t)q << 16] = f2bf(acc[q]);
}

// K3: dense v-conv fused with token gather + normalization.
// Conv identical to round 9 (launch_bounds(256,1) keeps the hoisted
// 79-value g window in VGPRs). Scatter loop now batches token meta as one
// int4 per 4 tokens (wave-cyclic chunks) — kills the per-token serial
// readfirstlane chain.
__global__ __launch_bounds__(256, 1) void k3_convv(
    const int* __restrict__ tokh, const int* __restrict__ cnth,
    const float* __restrict__ G2f, const ushort_t* __restrict__ B1,
    const float* __restrict__ invden, float* __restrict__ out, int b0)
{
    int ph   = blockIdx.x & 63;
    int dc   = (blockIdx.x >> 6) & 15;
    int b    = b0 + (blockIdx.x >> 10);
    int tid  = threadIdx.x;
    int lane = tid & 63;
    int w    = tid >> 6;
    int wq   = w << 4;                 // per-lane on purpose (VGPR g loads)
    int d0   = dc << 6;

    int n = cnth[b * 64 + ph];
    if (n == 0) return;               // uniform across block: safe

    __shared__ float u[64][64];       // staged B1 column; reused as y

    const ushort_t* B1p = B1 + (((size_t)(b - b0)) << 22) + (((size_t)ph) << 16)
                        + d0 + lane;
#pragma unroll
    for (int k = 0; k < 16; k++) {
        int j = (k << 2) + w;
        u[j][lane] = bf2f(B1p[(size_t)j << 10]);
    }

    const float* gq = G2f + 63 + wq;   // conv window: gq[-63 .. +15]

    float acc[16];
#pragma unroll
    for (int q = 0; q < 16; q++) acc[q] = 0.f;

    __syncthreads();

#pragma unroll
    for (int j = 0; j < 64; j += 4) {
        float uv[4];
#pragma unroll
        for (int jj = 0; jj < 4; jj++) uv[jj] = u[j + jj][lane];
#pragma unroll
        for (int q = 0; q < 16; q++) {
            float a = acc[q];
#pragma unroll
            for (int jj = 0; jj < 4; jj++)
                a = fmaf(gq[q - (j + jj)], uv[jj], a);
            acc[q] = a;
        }
    }
    __syncthreads();                   // all u reads complete
#pragma unroll
    for (int q = 0; q < 16; q++) u[wq + q][lane] = acc[q];   // y into u's LDS
    __syncthreads();

    const int* toks = tokh + ((size_t)(b * 64 + ph)) * CAP;
    float* outb = out + (((size_t)b * NT) << 10) + d0 + lane;
    const float* ivb = invden + ((b * 64) << 6) + ph;

    // scatter: wave-cyclic chunks of 4 tokens, one int4 meta load per chunk
    int nch = (n + 3) >> 2;
    for (int c = w; c < nch; c += 4) {
        int i0 = c << 2;
        int4 M = *(const int4*)(toks + i0);   // safe past n: ws mapped
        int pk[4];
        pk[0] = __builtin_amdgcn_readfirstlane(M.x);
        pk[1] = __builtin_amdgcn_readfirstlane(M.y);
        pk[2] = __builtin_amdgcn_readfirstlane(M.z);
        pk[3] = __builtin_amdgcn_readfirstlane(M.w);
#pragma unroll
        for (int j = 0; j < 4; j++) {
            if (i0 + j < n) {                 // uniform condition
                int t  = pk[j] & 0xffff;
                int pvt = pk[j] >> 16;
                float iv = ivb[pvt << 6];
                outb[(size_t)t << 10] = u[pvt][lane] * iv;
            }
        }
    }
}

// Safety-net fallback (no workspace needed): direct O(T^2 * D) attention.
__global__ __launch_bounds__(256) void k_naive(
    const float* __restrict__ x, const int* __restrict__ posv,
    const int* __restrict__ posh, float* __restrict__ out)
{
    int t   = blockIdx.x & (NT - 1);
    int b   = blockIdx.x >> 11;
    int tid = threadIdx.x;

    __shared__ float s_w[NT];
    __shared__ float s_red[256];

    int pvt = posv[b * NT + t];
    int pht = posh[b * NT + t];

    float dsum = 0.0f;
    for (int s = tid; s < NT; s += 256) {
        int dv = pvt - posv[b * NT + s];
        int dh = pht - posh[b * NT + s];
        float w = expf(-(float)(dv * dv + dh * dh) * (1.0f / 512.0f));
        s_w[s] = w;
        dsum += w;
    }
    s_red[tid] = dsum;
    __syncthreads();
    for (int off = 128; off > 0; off >>= 1) {
        if (tid < off) s_red[tid] += s_red[tid + off];
        __syncthreads();
    }
    float inv = 1.0f / s_red[0];

    float a0 = 0.f, a1 = 0.f, a2 = 0.f, a3 = 0.f;
    for (int s = 0; s < NT; s++) {
        float w = s_w[s];
        const float* xr = x + (((size_t)(b * NT + s)) << 10);
        a0 = fmaf(w, xr[tid + 0],   a0);
        a1 = fmaf(w, xr[tid + 256], a1);
        a2 = fmaf(w, xr[tid + 512], a2);
        a3 = fmaf(w, xr[tid + 768], a3);
    }
    size_t ob = (((size_t)(b * NT + t)) << 10) + tid;
    out[ob + 0]   = a0 * inv;
    out[ob + 256] = a1 * inv;
    out[ob + 512] = a2 * inv;
    out[ob + 768] = a3 * inv;
}

extern "C" void kernel_launch(void* const* d_in, const int* in_sizes, int n_in,
                              void* d_out, int out_size, void* d_ws, size_t ws_size,
                              hipStream_t stream) {
    const float* x    = (const float*)d_in[0];
    const int*   posv = (const int*)d_in[1];
    const int*   posh = (const int*)d_in[2];
    float*       out  = (float*)d_out;

    char* ws = (char*)d_ws;
    float*    gbase  = (float*)ws;               // pad + table
    float*    G2f    = (float*)(ws + OFF_G2);
    int*      cntv   = (int*)(ws + OFF_CNTV);
    int*      cnth   = (int*)(ws + OFF_CNTH);
    float*    invden = (float*)(ws + OFF_INVDEN);
    int*      tokv   = (int*)(ws + OFF_TOKV);
    int*      tokh   = (int*)(ws + OFF_TOKH);
    ushort_t* B1     = (ushort_t*)(ws + OFF_B1);

    const size_t needFull = (size_t)OFF_B1 + (size_t)NB * B1_SLAB;   // ~73 MB
    const size_t needLoop = (size_t)OFF_B1 + B1_SLAB;                // ~17 MB

    if (ws_size >= needFull) {
        k1_bucket<<<NB * 32, 256, 0, stream>>>(posv, posh, tokv, tokh, cntv, cnth, gbase);
        kden<<<NB * 8, 256, 0, stream>>>(posv, posh, G2f, invden, 0);
        k2_convh<<<NB * 1024, 256, 0, stream>>>(x, tokv, cntv, G2f, B1, 0);
        k3_convv<<<NB * 1024, 256, 0, stream>>>(tokh, cnth, G2f, B1, invden, out, 0);
    } else if (ws_size >= needLoop) {
        k1_bucket<<<NB * 32, 256, 0, stream>>>(posv, posh, tokv, tokh, cntv, cnth, gbase);
        for (int b = 0; b < NB; b++) {
            kden<<<8, 256, 0, stream>>>(posv, posh, G2f, invden, b);
            k2_convh<<<1024, 256, 0, stream>>>(x, tokv, cntv, G2f, B1, b);
            k3_convv<<<1024, 256, 0, stream>>>(tokh, cnth, G2f, B1, invden, out, b);
        }
    } else {
        k_naive<<<NB * NT, 256, 0, stream>>>(x, posv, posh, out);
    }
}